// Round 12
// baseline (253.455 us; speedup 1.0000x reference)
//
#include <hip/hip_runtime.h>
#include <math.h>

#define BATCH 2
#define TSTEPS 8

typedef __attribute__((ext_vector_type(8))) short s16x8;   // 8 bf16
typedef __attribute__((ext_vector_type(4))) float f32x4;   // MFMA accum

__device__ __forceinline__ float hsig(float v){ return fminf(fmaxf(0.2f*v+0.5f,0.f),1.f); }
__device__ __forceinline__ ushort f2bf(float f){
    uint u = __builtin_bit_cast(uint, f);
    u = (u + 0x7FFFu + ((u >> 16) & 1u)) >> 16;
    return (ushort)u;
}
__device__ __forceinline__ uint pack2bf(float lo, float hi){
    return (uint)f2bf(lo) | ((uint)f2bf(hi) << 16);
}

// zero one border uint4 of a padded [NIMG][HP][WP][C8*8] bf16 buffer.
template<int HP, int WP, int C8>
__device__ __forceinline__ void zero_border(ushort* __restrict__ base, int i){
    constexpr int BPX = 2*WP + 2*(HP-2);
    int c8 = i % C8; int rest = i / C8;
    int b = rest % BPX; int img = rest / BPX;
    int row, col;
    if (b < WP){ row = 0; col = b; }
    else if (b < 2*WP){ row = HP-1; col = b - WP; }
    else { int c = b - 2*WP; row = 1 + (c >> 1); col = (c & 1) ? (WP-1) : 0; }
    uint4 z = {0,0,0,0};
    *(uint4*)&base[(((size_t)img*HP + row)*WP + col)*(size_t)(C8*8) + c8*8] = z;
}

// ---------------------------------------------------------------------------
// Coalesced weight pack: one block per (tensor, c-group). Phase A: read the
// 32 x 4Co source rows coalesced (float4), bf16 into LDS with SP=4Co+8 pad
// (row-stride bank offset 4 -> 8-row gather conflict-free-ish). Phase B:
// build uint4 of 8 j-taps from 8 LDS rows, write dst coalesced.
// Replaces per-element packw whose source reads hit 1 fp32 per cacheline.
// ---------------------------------------------------------------------------
template<int KCH, int KCHP, int Co>
__device__ __forceinline__ void packc(const float* __restrict__ W,
                                      ushort* __restrict__ dst,
                                      int c, ushort* __restrict__ lds){
    const int tid = threadIdx.x;
    constexpr int SP  = 4*Co + 8;
    constexpr int NF4 = 32*Co;        // float4 loads (32 rows x 4Co floats)
    constexpr int NT  = Co/4;         // t_n count = 4*Co/16
    constexpr int NPAIR = NT*64;      // (t_n, lane) pairs -> one uint4 each
    if (c < KCH){
        for (int f = tid; f < NF4; f += 256){
            int row = f / Co, col4 = (f - row*Co)*4;
            float4 v = *(const float4*)(W + ((size_t)(c*32+row))*(4*Co) + col4);
            ushort4 b;
            b.x = f2bf(v.x); b.y = f2bf(v.y); b.z = f2bf(v.z); b.w = f2bf(v.w);
            *(ushort4*)&lds[row*SP + col4] = b;
        }
        __syncthreads();
        for (int p = tid; p < NPAIR; p += 256){
            int t_n = p >> 6, lane = p & 63;
            int q = lane >> 4, l = lane & 15;
            int np = t_n*16 + l, g = np & 3, co = np >> 2;
            const ushort* base = &lds[q*8*SP + g*Co + co];
            uint4 v;
            v.x = (uint)base[0]    | ((uint)base[SP]   << 16);
            v.y = (uint)base[2*SP] | ((uint)base[3*SP] << 16);
            v.z = (uint)base[4*SP] | ((uint)base[5*SP] << 16);
            v.w = (uint)base[6*SP] | ((uint)base[7*SP] << 16);
            *(uint4*)&dst[(((size_t)t_n*KCHP + c)*64 + lane)*8] = v;
        }
    } else {
        // K-pad c-group: exact zeros
        uint4 z = {0,0,0,0};
        for (int p = tid; p < NPAIR; p += 256){
            int t_n = p >> 6, lane = p & 63;
            *(uint4*)&dst[(((size_t)t_n*KCHP + c)*64 + lane)*8] = z;
        }
    }
}

#define SZ_WX1  917504   // 32 tiles * 56 * 512
#define SZ_WH1  589824   // 32 * 36 * 512
#define SZ_WX2  294912   // 16 * 36 * 512
#define SZ_WH2  163840   // 16 * 20 * 512
#define SZ_WX3   81920   //  8 * 20 * 512
#define SZ_WH3   49152   //  8 * 12 * 512

#define XP4     124416   // xpad full buffer in uint4 chunks (16*18*18*192/8)
#define XPB     486      // = XP4/256 exactly
#define PKB     180      // packc blocks: 56+36+36+20+20+12
// border-only zero segments (uint4 counts)
#define BZ2     33792
#define BZ3     33280
#define BZH1     4352
#define BZH2     4224
#define BZH3     4160
#define BZB     312      // ceil(79808/256)
#define PREP_BLOCKS (XPB + PKB + BZB)   // 978

struct Params {
    const float *x, *Wx1, *Wh1, *b1, *g1, *be1, *mm1, *mv1;
    const float *Wx2, *Wh2, *b2, *g2, *be2, *mm2, *mv2;
    const float *Wx3, *Wh3, *b3, *g3, *be3, *mm3, *mv3;
    float *c1, *c2, *c3;
    char  *zbase;
    ushort *xpad, *x2pad, *x3pad, *h1A, *h1B, *h2A, *h2B, *h3A, *h3B;
    ushort *Wxp1, *Wxp2, *Wxp3, *Whp1, *Whp2, *Whp3;
    float *out;
};

// merged pad + coalesced weight-pack + border-zero kernel
__global__ __launch_bounds__(256) void prep_zero_g(Params p){
    __shared__ ushort wlds[32*520];   // max SP tensor (Co=128): 33280 B
    int bid = blockIdx.x;
    const int tid = threadIdx.x;
    if (bid < XPB){
        int i = bid*256 + tid;        // i < XP4 exactly (486*256 == XP4)
        int c8 = i % 24; int r = i / 24;
        int xx = r % 18; r /= 18; int yy = r % 18; int bt = r / 18;
        uint4 v = {0,0,0,0};
        if (xx >= 1 && xx <= 16 && yy >= 1 && yy <= 16){
            const float* src = p.x + ((size_t)(bt*256 + (yy-1)*16 + (xx-1))*192 + c8*8);
            float4 f0 = *(const float4*)src;
            float4 f1 = *(const float4*)(src + 4);
            v.x = pack2bf(f0.x, f0.y); v.y = pack2bf(f0.z, f0.w);
            v.z = pack2bf(f1.x, f1.y); v.w = pack2bf(f1.z, f1.w);
        }
        *(uint4*)&p.xpad[((size_t)(bt*324 + yy*18 + xx)*192 + c8*8)] = v;
        return;
    } bid -= XPB;
    if (bid < 56){ packc<54,56,128>(p.Wx1, p.Wxp1, bid, wlds); return; } bid -= 56;
    if (bid < 36){ packc<36,36,128>(p.Wh1, p.Whp1, bid, wlds); return; } bid -= 36;
    if (bid < 36){ packc<36,36, 64>(p.Wx2, p.Wxp2, bid, wlds); return; } bid -= 36;
    if (bid < 20){ packc<18,20, 64>(p.Wh2, p.Whp2, bid, wlds); return; } bid -= 20;
    if (bid < 20){ packc<18,20, 32>(p.Wx3, p.Wxp3, bid, wlds); return; } bid -= 20;
    if (bid < 12){ packc< 9,12, 32>(p.Wh3, p.Whp3, bid, wlds); return; } bid -= 12;
    // border-only zeroing; every segment GUARDED (round-7 lesson).
    int i = bid*256 + tid;
    if (i < BZ2 ){ zero_border<34,34,16>(p.x2pad, i); return; } i -= BZ2;
    if (i < BZ3 ){ zero_border<66,66, 8>(p.x3pad, i); return; } i -= BZ3;
    if (i < BZH1){ zero_border<18,18,16>(p.h1A,  i); return; } i -= BZH1;
    if (i < BZH2){ zero_border<34,34, 8>(p.h2A,  i); return; } i -= BZH2;
    if (i < BZH3){ zero_border<66,66, 4>(p.h3A,  i); }
}

// ---------------------------------------------------------------------------
// Fused ConvLSTM step role. NCPB col-groups per block; K padded (branch-free).
// Zs sliced per-cc (LDS 28928 -> 5 blocks/CU). XCD swizzle: colB = lbid % NC.
// ---------------------------------------------------------------------------
template<int CI, int CO, int H, int W, int OUT_BF16, int NCPB>
__device__ __forceinline__ void fused_role(char* smem, int lbid, int t, int first,
    const ushort* __restrict__ Apad, const ushort* __restrict__ Wxpk,
    const ushort* __restrict__ hprev, const ushort* __restrict__ Whpk,
    const float* __restrict__ bias,
    ushort* __restrict__ hnew, float* __restrict__ cst,
    const float* __restrict__ gamma, const float* __restrict__ beta,
    const float* __restrict__ mmean, const float* __restrict__ mvar,
    void* __restrict__ outp)
{
    constexpr int W_T = (W < 32) ? W : 32;
    constexpr int PR = (32/W_T) + 2, PPX = W_T + 2;
    constexpr int PCI = CI + 8, PCO = CO + 8;
    constexpr int KX = 9*CI/32, CPTX = CI/32;
    constexpr int KH = 9*CO/32, CPTH = CO/32;
    constexpr int KXP = (KX + 3) & ~3, KHP = (KH + 3) & ~3;
    constexpr int NJX = KXP/4, NJH = KHP/4;
    constexpr int HW = H*W, HP = H+2, WP = W+2;
    constexpr int CH8X = CI/8, CH8H = CO/8;
    constexpr int TOTX = PR*PPX*CH8X, TOTH = PR*PPX*CH8H;
    constexpr int NC = (4*CO/32)/NCPB;

    ushort* patch = (ushort*)smem;
    float* Zs = (float*)smem;                 // overlay, ONE cc slice [4][32][36]
    float* Hs = (float*)(smem + 18432);       // [32][8]

    const int tid = threadIdx.x, lane = tid & 63, wave = tid >> 6;
    const int quad = lane >> 4, l16 = lane & 15;
    const int colB = lbid % NC, pxt = lbid / NC;   // colB fast -> XCD locality
    const int m0 = pxt * 32;
    const int b2 = m0 / HW, rem = m0 - b2*HW;
    const int y0 = rem / W, x0 = rem - (rem/W)*W;
    const int bt = b2*TSTEPS + t;

    f32x4 acc[NCPB][2][2] = {};

    int labaseX[2], labaseH[2];
    #pragma unroll
    for (int s = 0; s < 2; ++s){
        int pp = s*16 + l16;
        int rp = pp / W_T, xp = pp - rp*W_T;
        labaseX[s] = (rp*PPX + xp)*PCI + quad*8;
        labaseH[s] = (rp*PPX + xp)*PCO + quad*8;
    }

    // ---- phase 1: x-conv ----
    {
        const ushort* gsrc = Apad + (size_t)bt*HP*WP*CI;
        for (int c = tid; c < TOTX; c += 256){
            int pix = c / CH8X, ch = c - pix*CH8X;
            int prow = pix / PPX, ppx = pix - prow*PPX;
            *(uint4*)&patch[pix*PCI + ch*8] =
                *(const uint4*)(gsrc + ((size_t)(y0+prow)*WP + (x0+ppx))*CI + ch*8);
        }
        __syncthreads();

        const ushort* bp[NCPB][2];
        #pragma unroll
        for (int cc = 0; cc < NCPB; ++cc){
            const int tn = (colB*NCPB + cc)*2;
            bp[cc][0] = Wxpk + ((size_t)tn*KXP*64 + lane)*8;
            bp[cc][1] = Wxpk + ((size_t)(tn+1)*KXP*64 + lane)*8;
        }
        #pragma unroll
        for (int j = 0; j < NJX; ++j){
            const int it = wave + 4*j;
            const int itA = (it < KX) ? it : 0;
            const int tap = itA / CPTX, ci0 = (itA - tap*CPTX)*32;
            const int kh = tap/3, kw = tap - (tap/3)*3;
            const int off = (kh*PPX + kw)*PCI + ci0;
            s16x8 a0 = *(const s16x8*)&patch[labaseX[0] + off];
            s16x8 a1 = *(const s16x8*)&patch[labaseX[1] + off];
            #pragma unroll
            for (int cc = 0; cc < NCPB; ++cc){
                s16x8 b0 = *(const s16x8*)(bp[cc][0] + (size_t)it*512);
                s16x8 b1 = *(const s16x8*)(bp[cc][1] + (size_t)it*512);
                acc[cc][0][0] = __builtin_amdgcn_mfma_f32_16x16x32_bf16(a0, b0, acc[cc][0][0], 0,0,0);
                acc[cc][0][1] = __builtin_amdgcn_mfma_f32_16x16x32_bf16(a0, b1, acc[cc][0][1], 0,0,0);
                acc[cc][1][0] = __builtin_amdgcn_mfma_f32_16x16x32_bf16(a1, b0, acc[cc][1][0], 0,0,0);
                acc[cc][1][1] = __builtin_amdgcn_mfma_f32_16x16x32_bf16(a1, b1, acc[cc][1][1], 0,0,0);
            }
        }
        __syncthreads();   // x-patch dead
    }

    // ---- phase 2: h-conv (skipped at t==0; h==0) ----
    if (!first){
        const ushort* gsrc = hprev + (size_t)b2*HP*WP*CO;
        for (int c = tid; c < TOTH; c += 256){
            int pix = c / CH8H, ch = c - pix*CH8H;
            int prow = pix / PPX, ppx = pix - prow*PPX;
            *(uint4*)&patch[pix*PCO + ch*8] =
                *(const uint4*)(gsrc + ((size_t)(y0+prow)*WP + (x0+ppx))*CO + ch*8);
        }
        __syncthreads();

        const ushort* bp[NCPB][2];
        #pragma unroll
        for (int cc = 0; cc < NCPB; ++cc){
            const int tn = (colB*NCPB + cc)*2;
            bp[cc][0] = Whpk + ((size_t)tn*KHP*64 + lane)*8;
            bp[cc][1] = Whpk + ((size_t)(tn+1)*KHP*64 + lane)*8;
        }
        #pragma unroll
        for (int j = 0; j < NJH; ++j){
            const int it = wave + 4*j;
            const int itA = (it < KH) ? it : 0;
            const int tap = itA / CPTH, ci0 = (itA - tap*CPTH)*32;
            const int kh = tap/3, kw = tap - (tap/3)*3;
            const int off = (kh*PPX + kw)*PCO + ci0;
            s16x8 a0 = *(const s16x8*)&patch[labaseH[0] + off];
            s16x8 a1 = *(const s16x8*)&patch[labaseH[1] + off];
            #pragma unroll
            for (int cc = 0; cc < NCPB; ++cc){
                s16x8 b0 = *(const s16x8*)(bp[cc][0] + (size_t)it*512);
                s16x8 b1 = *(const s16x8*)(bp[cc][1] + (size_t)it*512);
                acc[cc][0][0] = __builtin_amdgcn_mfma_f32_16x16x32_bf16(a0, b0, acc[cc][0][0], 0,0,0);
                acc[cc][0][1] = __builtin_amdgcn_mfma_f32_16x16x32_bf16(a0, b1, acc[cc][0][1], 0,0,0);
                acc[cc][1][0] = __builtin_amdgcn_mfma_f32_16x16x32_bf16(a1, b0, acc[cc][1][0], 0,0,0);
                acc[cc][1][1] = __builtin_amdgcn_mfma_f32_16x16x32_bf16(a1, b1, acc[cc][1][1], 0,0,0);
            }
        }
        __syncthreads();   // h-patch dead
    }

    // ---- phases 3-5, sliced per col-group cc ----
    #pragma unroll
    for (int cc = 0; cc < NCPB; ++cc){
        #pragma unroll
        for (int s = 0; s < 2; ++s)
            #pragma unroll
            for (int nt = 0; nt < 2; ++nt)
                #pragma unroll
                for (int r = 0; r < 4; ++r)
                    Zs[(wave*32 + s*16 + quad*4 + r)*36 + nt*16 + l16] = acc[cc][s][nt][r];
        __syncthreads();

        {
            const int px = tid >> 3, coin = tid & 7;
            const int m = m0 + px;
            const int rr = m - b2*HW;
            const int co = (colB*NCPB + cc)*8 + coin;
            float zi = 0.f, zf = 0.f, zg = 0.f, zo = 0.f;
            #pragma unroll
            for (int w = 0; w < 4; ++w){
                const float4 s = *(const float4*)&Zs[(w*32 + px)*36 + coin*4];
                zi += s.x; zf += s.y; zg += s.z; zo += s.w;
            }
            zi += bias[0*CO + co]; zf += bias[1*CO + co];
            zg += bias[2*CO + co]; zo += bias[3*CO + co];
            const float iv = hsig(zi), fv = hsig(zf);
            const float gv = tanhf(zg), ov = hsig(zo);
            const float cold = first ? 0.f : cst[(size_t)m*CO + co];
            const float cn = fv*cold + iv*gv;
            cst[(size_t)m*CO + co] = cn;
            const float h = ov * tanhf(cn);
            const int y = rr / W, x = rr - (rr/W)*W;
            hnew[((size_t)b2*HP*WP + (y+1)*WP + (x+1))*CO + co] = f2bf(h);
            Hs[px*8 + coin] = (h - mmean[co])*rsqrtf(mvar[co]+1e-3f)*gamma[co] + beta[co];
        }
        __syncthreads();

        {
            const int co0 = (colB*NCPB + cc)*8;
            if (OUT_BF16){
                if (tid < 128){
                    const int px = tid >> 2, q = tid & 3;
                    const int ypos = q >> 1, xpos = q & 1;
                    const int m = m0 + px;
                    const int rr = m - b2*HW;
                    const int y = rr / W, x = rr - (rr/W)*W;
                    const float* hs = &Hs[px*8];
                    uint4 v;
                    v.x = pack2bf(hs[0], hs[1]); v.y = pack2bf(hs[2], hs[3]);
                    v.z = pack2bf(hs[4], hs[5]); v.w = pack2bf(hs[6], hs[7]);
                    ushort* o = (ushort*)outp;
                    const size_t opix = ((size_t)bt*(2*H+2) + 2*y+1+ypos)*(size_t)(2*W+2) + 2*x+1+xpos;
                    *(uint4*)&o[opix*CO + co0] = v;
                }
            } else {
                const int px = tid >> 3, q = (tid >> 1) & 3, half = tid & 1;
                const int ypos = q >> 1, xpos = q & 1;
                const int m = m0 + px;
                const int rr = m - b2*HW;
                const int y = rr / W, x = rr - (rr/W)*W;
                float4 v = *(const float4*)&Hs[px*8 + half*4];
                float* o = (float*)outp;
                const size_t opix = ((size_t)bt*(2*H) + 2*y+ypos)*(size_t)(2*W) + 2*x+xpos;
                *(float4*)&o[opix*CO + co0 + half*4] = v;
            }
        }
        if (cc + 1 < NCPB) __syncthreads();
    }
}

// ---------------------------------------------------------------------------
// Mega: {S1f (NCPB=1, 256), S2f (NCPB=1, 512), S3f (NCPB=2, 512)}.
// LDS = 28928 B -> 5 blocks/CU; steady grid = 1280 = 5/CU x 256 CU.
// ---------------------------------------------------------------------------
__global__ __launch_bounds__(256, 5) void mega(Params p, int e1, int e2,
                                               int t1, int t2, int t3)
{
    __shared__ __align__(16) char smem[28928];
    const int bid = blockIdx.x;
    if (bid < e1){
        const ushort* hp = (t1 & 1) ? p.h1B : p.h1A;
        ushort*       hn = (t1 & 1) ? p.h1A : p.h1B;
        fused_role<192,128,16,16,1,1>(smem, bid, t1, t1==0,
            p.xpad, p.Wxp1, hp, p.Whp1, p.b1, hn, p.c1,
            p.g1, p.be1, p.mm1, p.mv1, p.x2pad);
    } else if (bid < e2){
        const ushort* hp = (t2 & 1) ? p.h2B : p.h2A;
        ushort*       hn = (t2 & 1) ? p.h2A : p.h2B;
        fused_role<128,64,32,32,1,1>(smem, bid - e1, t2, t2==0,
            p.x2pad, p.Wxp2, hp, p.Whp2, p.b2, hn, p.c2,
            p.g2, p.be2, p.mm2, p.mv2, p.x3pad);
    } else {
        const ushort* hp = (t3 & 1) ? p.h3B : p.h3A;
        ushort*       hn = (t3 & 1) ? p.h3A : p.h3B;
        fused_role<64,32,64,64,0,2>(smem, bid - e2, t3, t3==0,
            p.x3pad, p.Wxp3, hp, p.Whp3, p.b3, hn, p.c3,
            p.g3, p.be3, p.mm3, p.mv3, p.out);
    }
}

extern "C" void kernel_launch(void* const* d_in, const int* in_sizes, int n_in,
                              void* d_out, int out_size, void* d_ws, size_t ws_size,
                              hipStream_t stream) {
    Params p;
    p.x   = (const float*)d_in[0];
    p.Wx1 = (const float*)d_in[1];  p.Wh1 = (const float*)d_in[2];
    p.b1  = (const float*)d_in[3];  p.g1  = (const float*)d_in[4];
    p.be1 = (const float*)d_in[5];  p.mm1 = (const float*)d_in[6];
    p.mv1 = (const float*)d_in[7];
    p.Wx2 = (const float*)d_in[8];  p.Wh2 = (const float*)d_in[9];
    p.b2  = (const float*)d_in[10]; p.g2  = (const float*)d_in[11];
    p.be2 = (const float*)d_in[12]; p.mm2 = (const float*)d_in[13];
    p.mv2 = (const float*)d_in[14];
    p.Wx3 = (const float*)d_in[15]; p.Wh3 = (const float*)d_in[16];
    p.b3  = (const float*)d_in[17]; p.g3  = (const float*)d_in[18];
    p.be3 = (const float*)d_in[19]; p.mm3 = (const float*)d_in[20];
    p.mv3 = (const float*)d_in[21];

    char* ws = (char*)d_ws;
    size_t off = 0;
    auto alloc = [&](size_t bytes) { char* q = ws + off; off += (bytes + 255) & ~(size_t)255; return q; };

    p.c1  = (float*)alloc(65536ull * 4);
    p.c2  = (float*)alloc(131072ull * 4);
    p.c3  = (float*)alloc(262144ull * 4);

    p.zbase = alloc(17685504ull);
    p.xpad  = (ushort*)p.zbase;
    p.x2pad = p.xpad  + 995328;
    p.x3pad = p.x2pad + 2367488;
    p.h1A   = p.x3pad + 4460544;
    p.h1B   = p.h1A + 82944;
    p.h2A   = p.h1B + 82944;
    p.h2B   = p.h2A + 147968;
    p.h3A   = p.h2B + 147968;
    p.h3B   = p.h3A + 278784;

    p.Wxp1 = (ushort*)alloc((size_t)SZ_WX1 * 2);
    p.Wxp2 = (ushort*)alloc((size_t)SZ_WX2 * 2);
    p.Wxp3 = (ushort*)alloc((size_t)SZ_WX3 * 2);
    p.Whp1 = (ushort*)alloc((size_t)SZ_WH1 * 2);
    p.Whp2 = (ushort*)alloc((size_t)SZ_WH2 * 2);
    p.Whp3 = (ushort*)alloc((size_t)SZ_WH3 * 2);

    p.out = (float*)d_out;

    prep_zero_g<<<PREP_BLOCKS, 256, 0, stream>>>(p);

    // pipeline: launch j runs { S1f(j), S2f(j-1), S3f(j-2) }
    for (int j = 0; j <= 9; ++j){
        const int aS1 = (j <= 7);
        const int aS2 = (j >= 1 && j <= 8);
        const int aS3 = (j >= 2);
        const int e1 = aS1 ? 256 : 0;
        const int e2 = e1 + (aS2 ? 512 : 0);
        const int e3 = e2 + (aS3 ? 512 : 0);
        const int t1 = aS1 ? j     : 0;
        const int t2 = aS2 ? j - 1 : 0;
        const int t3 = aS3 ? j - 2 : 0;
        mega<<<dim3(e3), 256, 0, stream>>>(p, e1, e2, t1, t2, t3);
    }
}

// Round 13
// 242.407 us; speedup vs baseline: 1.0456x; 1.0456x over previous
//
#include <hip/hip_runtime.h>
#include <math.h>

#define BATCH 2
#define TSTEPS 8

typedef __attribute__((ext_vector_type(8))) short s16x8;   // 8 bf16
typedef __attribute__((ext_vector_type(4))) float f32x4;   // MFMA accum

__device__ __forceinline__ float hsig(float v){ return fminf(fmaxf(0.2f*v+0.5f,0.f),1.f); }
__device__ __forceinline__ ushort f2bf(float f){
    uint u = __builtin_bit_cast(uint, f);
    u = (u + 0x7FFFu + ((u >> 16) & 1u)) >> 16;
    return (ushort)u;
}
__device__ __forceinline__ uint pack2bf(float lo, float hi){
    return (uint)f2bf(lo) | ((uint)f2bf(hi) << 16);
}

// pack W[k][g*Co+co] fp32 -> fragment-linear bf16, K padded to KCHP (zeros)
template<int KCH, int KCHP, int Co>
__device__ __forceinline__ void packw(const float* __restrict__ W, ushort* __restrict__ dst, int d){
    int j = d & 7, lane = (d >> 3) & 63;
    int q = lane >> 4, l = lane & 15;
    int rest = d >> 9;
    int c = rest % KCHP, t_n = rest / KCHP;
    if (c >= KCH){ dst[d] = 0; return; }
    int k = c*32 + q*8 + j;
    int np = t_n*16 + l;
    int g = np & 3, co = np >> 2;
    dst[d] = f2bf(W[(size_t)k*(4*Co) + g*Co + co]);
}

// zero one border uint4 of a padded [NIMG][HP][WP][C8*8] bf16 buffer.
// Border pixels: top row, bottom row, left col, right col (halo ring).
// Interiors are fully rewritten each step before read -> never need zeroing.
template<int HP, int WP, int C8>
__device__ __forceinline__ void zero_border(ushort* __restrict__ base, int i){
    constexpr int BPX = 2*WP + 2*(HP-2);
    int c8 = i % C8; int rest = i / C8;
    int b = rest % BPX; int img = rest / BPX;
    int row, col;
    if (b < WP){ row = 0; col = b; }
    else if (b < 2*WP){ row = HP-1; col = b - WP; }
    else { int c = b - 2*WP; row = 1 + (c >> 1); col = (c & 1) ? (WP-1) : 0; }
    uint4 z = {0,0,0,0};
    *(uint4*)&base[(((size_t)img*HP + row)*WP + col)*(size_t)(C8*8) + c8*8] = z;
}

#define SZ_WX1  917504   // 32 tiles * 56 * 512
#define SZ_WH1  589824   // 32 * 36 * 512
#define SZ_WX2  294912   // 16 * 36 * 512
#define SZ_WH2  163840   // 16 * 20 * 512
#define SZ_WX3   81920   //  8 * 20 * 512
#define SZ_WH3   49152   //  8 * 12 * 512
#define SZ_W    (SZ_WX1+SZ_WH1+SZ_WX2+SZ_WH2+SZ_WX3+SZ_WH3)   // 2,097,152

#define XP4     124416   // xpad full buffer in uint4 chunks (16*18*18*192/8)
// border-only zero segments (uint4 counts)
#define BZ2     33792    // x2pad: 16 img * 132 border px * 16 u4
#define BZ3     33280    // x3pad: 16 * 260 * 8
#define BZH1     4352    // h1A..h1B: 4 img * 68 * 16
#define BZH2     4224    // h2A..h2B: 4 * 132 * 8
#define BZH3     4160    // h3A..h3B: 4 * 260 * 4
#define TOT_PREP (XP4 + SZ_W + BZ2 + BZ3 + BZH1 + BZH2 + BZH3)

struct Params {
    const float *x, *Wx1, *Wh1, *b1, *g1, *be1, *mm1, *mv1;
    const float *Wx2, *Wh2, *b2, *g2, *be2, *mm2, *mv2;
    const float *Wx3, *Wh3, *b3, *g3, *be3, *mm3, *mv3;
    float *c1, *c2, *c3;
    char  *zbase;
    ushort *xpad, *x2pad, *x3pad, *h1A, *h1B, *h2A, *h2B, *h3A, *h3B;
    ushort *Wxp1, *Wxp2, *Wxp3, *Whp1, *Whp2, *Whp3;
    float *out;
};

// merged pad + weight-pack + border-zero kernel (no bulk memset anywhere)
__global__ __launch_bounds__(256) void prep_zero_g(Params p){
    int i = blockIdx.x*256 + threadIdx.x;
    if (i < XP4){
        int c8 = i % 24; int r = i / 24;
        int xx = r % 18; r /= 18; int yy = r % 18; int bt = r / 18;
        uint4 v = {0,0,0,0};
        if (xx >= 1 && xx <= 16 && yy >= 1 && yy <= 16){
            const float* src = p.x + ((size_t)(bt*256 + (yy-1)*16 + (xx-1))*192 + c8*8);
            float4 f0 = *(const float4*)src;
            float4 f1 = *(const float4*)(src + 4);
            v.x = pack2bf(f0.x, f0.y); v.y = pack2bf(f0.z, f0.w);
            v.z = pack2bf(f1.x, f1.y); v.w = pack2bf(f1.z, f1.w);
        }
        *(uint4*)&p.xpad[((size_t)(bt*324 + yy*18 + xx)*192 + c8*8)] = v;
        return;
    } i -= XP4;
    if (i < SZ_WX1){ packw<54,56,128>(p.Wx1, p.Wxp1, i); return; } i -= SZ_WX1;
    if (i < SZ_WH1){ packw<36,36,128>(p.Wh1, p.Whp1, i); return; } i -= SZ_WH1;
    if (i < SZ_WX2){ packw<36,36, 64>(p.Wx2, p.Wxp2, i); return; } i -= SZ_WX2;
    if (i < SZ_WH2){ packw<18,20, 64>(p.Wh2, p.Whp2, i); return; } i -= SZ_WH2;
    if (i < SZ_WX3){ packw<18,20, 32>(p.Wx3, p.Wxp3, i); return; } i -= SZ_WX3;
    if (i < SZ_WH3){ packw< 9,12, 32>(p.Wh3, p.Whp3, i); return; } i -= SZ_WH3;
    // border-only zeroing; every segment GUARDED (round-7 lesson: grid slack
    // threads must not fall into an unguarded write).
    if (i < BZ2 ){ zero_border<34,34,16>(p.x2pad, i); return; } i -= BZ2;
    if (i < BZ3 ){ zero_border<66,66, 8>(p.x3pad, i); return; } i -= BZ3;
    if (i < BZH1){ zero_border<18,18,16>(p.h1A,  i); return; } i -= BZH1;
    if (i < BZH2){ zero_border<34,34, 8>(p.h2A,  i); return; } i -= BZH2;
    if (i < BZH3){ zero_border<66,66, 4>(p.h3A,  i); }
}

// ---------------------------------------------------------------------------
// Fused ConvLSTM step role. NCPB col-groups per block; K padded (branch-free).
// Zs sliced per-cc (LDS 28928 -> 5 blocks/CU). XCD swizzle: colB = lbid % NC.
// ---------------------------------------------------------------------------
template<int CI, int CO, int H, int W, int OUT_BF16, int NCPB>
__device__ __forceinline__ void fused_role(char* smem, int lbid, int t, int first,
    const ushort* __restrict__ Apad, const ushort* __restrict__ Wxpk,
    const ushort* __restrict__ hprev, const ushort* __restrict__ Whpk,
    const float* __restrict__ bias,
    ushort* __restrict__ hnew, float* __restrict__ cst,
    const float* __restrict__ gamma, const float* __restrict__ beta,
    const float* __restrict__ mmean, const float* __restrict__ mvar,
    void* __restrict__ outp)
{
    constexpr int W_T = (W < 32) ? W : 32;
    constexpr int PR = (32/W_T) + 2, PPX = W_T + 2;
    constexpr int PCI = CI + 8, PCO = CO + 8;
    constexpr int KX = 9*CI/32, CPTX = CI/32;
    constexpr int KH = 9*CO/32, CPTH = CO/32;
    constexpr int KXP = (KX + 3) & ~3, KHP = (KH + 3) & ~3;
    constexpr int NJX = KXP/4, NJH = KHP/4;
    constexpr int HW = H*W, HP = H+2, WP = W+2;
    constexpr int CH8X = CI/8, CH8H = CO/8;
    constexpr int TOTX = PR*PPX*CH8X, TOTH = PR*PPX*CH8H;
    constexpr int NC = (4*CO/32)/NCPB;

    ushort* patch = (ushort*)smem;
    float* Zs = (float*)smem;                 // overlay, ONE cc slice [4][32][36]
    float* Hs = (float*)(smem + 18432);       // [32][8]

    const int tid = threadIdx.x, lane = tid & 63, wave = tid >> 6;
    const int quad = lane >> 4, l16 = lane & 15;
    const int colB = lbid % NC, pxt = lbid / NC;   // colB fast -> XCD locality
    const int m0 = pxt * 32;
    const int b2 = m0 / HW, rem = m0 - b2*HW;
    const int y0 = rem / W, x0 = rem - (rem/W)*W;
    const int bt = b2*TSTEPS + t;

    f32x4 acc[NCPB][2][2] = {};

    int labaseX[2], labaseH[2];
    #pragma unroll
    for (int s = 0; s < 2; ++s){
        int pp = s*16 + l16;
        int rp = pp / W_T, xp = pp - rp*W_T;
        labaseX[s] = (rp*PPX + xp)*PCI + quad*8;
        labaseH[s] = (rp*PPX + xp)*PCO + quad*8;
    }

    // ---- phase 1: x-conv ----
    {
        const ushort* gsrc = Apad + (size_t)bt*HP*WP*CI;
        for (int c = tid; c < TOTX; c += 256){
            int pix = c / CH8X, ch = c - pix*CH8X;
            int prow = pix / PPX, ppx = pix - prow*PPX;
            *(uint4*)&patch[pix*PCI + ch*8] =
                *(const uint4*)(gsrc + ((size_t)(y0+prow)*WP + (x0+ppx))*CI + ch*8);
        }
        __syncthreads();

        const ushort* bp[NCPB][2];
        #pragma unroll
        for (int cc = 0; cc < NCPB; ++cc){
            const int tn = (colB*NCPB + cc)*2;
            bp[cc][0] = Wxpk + ((size_t)tn*KXP*64 + lane)*8;
            bp[cc][1] = Wxpk + ((size_t)(tn+1)*KXP*64 + lane)*8;
        }
        #pragma unroll
        for (int j = 0; j < NJX; ++j){
            const int it = wave + 4*j;
            const int itA = (it < KX) ? it : 0;
            const int tap = itA / CPTX, ci0 = (itA - tap*CPTX)*32;
            const int kh = tap/3, kw = tap - (tap/3)*3;
            const int off = (kh*PPX + kw)*PCI + ci0;
            s16x8 a0 = *(const s16x8*)&patch[labaseX[0] + off];
            s16x8 a1 = *(const s16x8*)&patch[labaseX[1] + off];
            #pragma unroll
            for (int cc = 0; cc < NCPB; ++cc){
                s16x8 b0 = *(const s16x8*)(bp[cc][0] + (size_t)it*512);
                s16x8 b1 = *(const s16x8*)(bp[cc][1] + (size_t)it*512);
                acc[cc][0][0] = __builtin_amdgcn_mfma_f32_16x16x32_bf16(a0, b0, acc[cc][0][0], 0,0,0);
                acc[cc][0][1] = __builtin_amdgcn_mfma_f32_16x16x32_bf16(a0, b1, acc[cc][0][1], 0,0,0);
                acc[cc][1][0] = __builtin_amdgcn_mfma_f32_16x16x32_bf16(a1, b0, acc[cc][1][0], 0,0,0);
                acc[cc][1][1] = __builtin_amdgcn_mfma_f32_16x16x32_bf16(a1, b1, acc[cc][1][1], 0,0,0);
            }
        }
        __syncthreads();   // x-patch dead
    }

    // ---- phase 2: h-conv (skipped at t==0; h==0) ----
    if (!first){
        const ushort* gsrc = hprev + (size_t)b2*HP*WP*CO;
        for (int c = tid; c < TOTH; c += 256){
            int pix = c / CH8H, ch = c - pix*CH8H;
            int prow = pix / PPX, ppx = pix - prow*PPX;
            *(uint4*)&patch[pix*PCO + ch*8] =
                *(const uint4*)(gsrc + ((size_t)(y0+prow)*WP + (x0+ppx))*CO + ch*8);
        }
        __syncthreads();

        const ushort* bp[NCPB][2];
        #pragma unroll
        for (int cc = 0; cc < NCPB; ++cc){
            const int tn = (colB*NCPB + cc)*2;
            bp[cc][0] = Whpk + ((size_t)tn*KHP*64 + lane)*8;
            bp[cc][1] = Whpk + ((size_t)(tn+1)*KHP*64 + lane)*8;
        }
        #pragma unroll
        for (int j = 0; j < NJH; ++j){
            const int it = wave + 4*j;
            const int itA = (it < KH) ? it : 0;
            const int tap = itA / CPTH, ci0 = (itA - tap*CPTH)*32;
            const int kh = tap/3, kw = tap - (tap/3)*3;
            const int off = (kh*PPX + kw)*PCO + ci0;
            s16x8 a0 = *(const s16x8*)&patch[labaseH[0] + off];
            s16x8 a1 = *(const s16x8*)&patch[labaseH[1] + off];
            #pragma unroll
            for (int cc = 0; cc < NCPB; ++cc){
                s16x8 b0 = *(const s16x8*)(bp[cc][0] + (size_t)it*512);
                s16x8 b1 = *(const s16x8*)(bp[cc][1] + (size_t)it*512);
                acc[cc][0][0] = __builtin_amdgcn_mfma_f32_16x16x32_bf16(a0, b0, acc[cc][0][0], 0,0,0);
                acc[cc][0][1] = __builtin_amdgcn_mfma_f32_16x16x32_bf16(a0, b1, acc[cc][0][1], 0,0,0);
                acc[cc][1][0] = __builtin_amdgcn_mfma_f32_16x16x32_bf16(a1, b0, acc[cc][1][0], 0,0,0);
                acc[cc][1][1] = __builtin_amdgcn_mfma_f32_16x16x32_bf16(a1, b1, acc[cc][1][1], 0,0,0);
            }
        }
        __syncthreads();   // h-patch dead
    }

    // ---- phases 3-5, sliced per col-group cc ----
    #pragma unroll
    for (int cc = 0; cc < NCPB; ++cc){
        #pragma unroll
        for (int s = 0; s < 2; ++s)
            #pragma unroll
            for (int nt = 0; nt < 2; ++nt)
                #pragma unroll
                for (int r = 0; r < 4; ++r)
                    Zs[(wave*32 + s*16 + quad*4 + r)*36 + nt*16 + l16] = acc[cc][s][nt][r];
        __syncthreads();

        {
            const int px = tid >> 3, coin = tid & 7;
            const int m = m0 + px;
            const int rr = m - b2*HW;
            const int co = (colB*NCPB + cc)*8 + coin;
            float zi = 0.f, zf = 0.f, zg = 0.f, zo = 0.f;
            #pragma unroll
            for (int w = 0; w < 4; ++w){
                const float4 s = *(const float4*)&Zs[(w*32 + px)*36 + coin*4];
                zi += s.x; zf += s.y; zg += s.z; zo += s.w;
            }
            zi += bias[0*CO + co]; zf += bias[1*CO + co];
            zg += bias[2*CO + co]; zo += bias[3*CO + co];
            const float iv = hsig(zi), fv = hsig(zf);
            const float gv = tanhf(zg), ov = hsig(zo);
            const float cold = first ? 0.f : cst[(size_t)m*CO + co];
            const float cn = fv*cold + iv*gv;
            cst[(size_t)m*CO + co] = cn;
            const float h = ov * tanhf(cn);
            const int y = rr / W, x = rr - (rr/W)*W;
            hnew[((size_t)b2*HP*WP + (y+1)*WP + (x+1))*CO + co] = f2bf(h);
            Hs[px*8 + coin] = (h - mmean[co])*rsqrtf(mvar[co]+1e-3f)*gamma[co] + beta[co];
        }
        __syncthreads();

        {
            const int co0 = (colB*NCPB + cc)*8;
            if (OUT_BF16){
                if (tid < 128){
                    const int px = tid >> 2, q = tid & 3;
                    const int ypos = q >> 1, xpos = q & 1;
                    const int m = m0 + px;
                    const int rr = m - b2*HW;
                    const int y = rr / W, x = rr - (rr/W)*W;
                    const float* hs = &Hs[px*8];
                    uint4 v;
                    v.x = pack2bf(hs[0], hs[1]); v.y = pack2bf(hs[2], hs[3]);
                    v.z = pack2bf(hs[4], hs[5]); v.w = pack2bf(hs[6], hs[7]);
                    ushort* o = (ushort*)outp;
                    const size_t opix = ((size_t)bt*(2*H+2) + 2*y+1+ypos)*(size_t)(2*W+2) + 2*x+1+xpos;
                    *(uint4*)&o[opix*CO + co0] = v;
                }
            } else {
                const int px = tid >> 3, q = (tid >> 1) & 3, half = tid & 1;
                const int ypos = q >> 1, xpos = q & 1;
                const int m = m0 + px;
                const int rr = m - b2*HW;
                const int y = rr / W, x = rr - (rr/W)*W;
                float4 v = *(const float4*)&Hs[px*8 + half*4];
                float* o = (float*)outp;
                const size_t opix = ((size_t)bt*(2*H) + 2*y+ypos)*(size_t)(2*W) + 2*x+xpos;
                *(float4*)&o[opix*CO + co0 + half*4] = v;
            }
        }
        if (cc + 1 < NCPB) __syncthreads();
    }
}

// ---------------------------------------------------------------------------
// Mega: {S1f (NCPB=1, 256), S2f (NCPB=1, 512), S3f (NCPB=2, 512)}.
// LDS = 28928 B -> 5 blocks/CU; steady grid = 1280 = 5/CU x 256 CU.
// ---------------------------------------------------------------------------
__global__ __launch_bounds__(256, 5) void mega(Params p, int e1, int e2,
                                               int t1, int t2, int t3)
{
    __shared__ __align__(16) char smem[28928];
    const int bid = blockIdx.x;
    if (bid < e1){
        const ushort* hp = (t1 & 1) ? p.h1B : p.h1A;
        ushort*       hn = (t1 & 1) ? p.h1A : p.h1B;
        fused_role<192,128,16,16,1,1>(smem, bid, t1, t1==0,
            p.xpad, p.Wxp1, hp, p.Whp1, p.b1, hn, p.c1,
            p.g1, p.be1, p.mm1, p.mv1, p.x2pad);
    } else if (bid < e2){
        const ushort* hp = (t2 & 1) ? p.h2B : p.h2A;
        ushort*       hn = (t2 & 1) ? p.h2A : p.h2B;
        fused_role<128,64,32,32,1,1>(smem, bid - e1, t2, t2==0,
            p.x2pad, p.Wxp2, hp, p.Whp2, p.b2, hn, p.c2,
            p.g2, p.be2, p.mm2, p.mv2, p.x3pad);
    } else {
        const ushort* hp = (t3 & 1) ? p.h3B : p.h3A;
        ushort*       hn = (t3 & 1) ? p.h3A : p.h3B;
        fused_role<64,32,64,64,0,2>(smem, bid - e2, t3, t3==0,
            p.x3pad, p.Wxp3, hp, p.Whp3, p.b3, hn, p.c3,
            p.g3, p.be3, p.mm3, p.mv3, p.out);
    }
}

extern "C" void kernel_launch(void* const* d_in, const int* in_sizes, int n_in,
                              void* d_out, int out_size, void* d_ws, size_t ws_size,
                              hipStream_t stream) {
    Params p;
    p.x   = (const float*)d_in[0];
    p.Wx1 = (const float*)d_in[1];  p.Wh1 = (const float*)d_in[2];
    p.b1  = (const float*)d_in[3];  p.g1  = (const float*)d_in[4];
    p.be1 = (const float*)d_in[5];  p.mm1 = (const float*)d_in[6];
    p.mv1 = (const float*)d_in[7];
    p.Wx2 = (const float*)d_in[8];  p.Wh2 = (const float*)d_in[9];
    p.b2  = (const float*)d_in[10]; p.g2  = (const float*)d_in[11];
    p.be2 = (const float*)d_in[12]; p.mm2 = (const float*)d_in[13];
    p.mv2 = (const float*)d_in[14];
    p.Wx3 = (const float*)d_in[15]; p.Wh3 = (const float*)d_in[16];
    p.b3  = (const float*)d_in[17]; p.g3  = (const float*)d_in[18];
    p.be3 = (const float*)d_in[19]; p.mm3 = (const float*)d_in[20];
    p.mv3 = (const float*)d_in[21];

    char* ws = (char*)d_ws;
    size_t off = 0;
    auto alloc = [&](size_t bytes) { char* q = ws + off; off += (bytes + 255) & ~(size_t)255; return q; };

    p.c1  = (float*)alloc(65536ull * 4);
    p.c2  = (float*)alloc(131072ull * 4);
    p.c3  = (float*)alloc(262144ull * 4);

    p.zbase = alloc(17685504ull);
    p.xpad  = (ushort*)p.zbase;
    p.x2pad = p.xpad  + 995328;
    p.x3pad = p.x2pad + 2367488;
    p.h1A   = p.x3pad + 4460544;
    p.h1B   = p.h1A + 82944;
    p.h2A   = p.h1B + 82944;
    p.h2B   = p.h2A + 147968;
    p.h3A   = p.h2B + 147968;
    p.h3B   = p.h3A + 278784;

    p.Wxp1 = (ushort*)alloc((size_t)SZ_WX1 * 2);
    p.Wxp2 = (ushort*)alloc((size_t)SZ_WX2 * 2);
    p.Wxp3 = (ushort*)alloc((size_t)SZ_WX3 * 2);
    p.Whp1 = (ushort*)alloc((size_t)SZ_WH1 * 2);
    p.Whp2 = (ushort*)alloc((size_t)SZ_WH2 * 2);
    p.Whp3 = (ushort*)alloc((size_t)SZ_WH3 * 2);

    p.out = (float*)d_out;

    prep_zero_g<<<(TOT_PREP + 255) / 256, 256, 0, stream>>>(p);

    // pipeline: launch j runs { S1f(j), S2f(j-1), S3f(j-2) }
    for (int j = 0; j <= 9; ++j){
        const int aS1 = (j <= 7);
        const int aS2 = (j >= 1 && j <= 8);
        const int aS3 = (j >= 2);
        const int e1 = aS1 ? 256 : 0;
        const int e2 = e1 + (aS2 ? 512 : 0);
        const int e3 = e2 + (aS3 ? 512 : 0);
        const int t1 = aS1 ? j     : 0;
        const int t2 = aS2 ? j - 1 : 0;
        const int t3 = aS3 ? j - 2 : 0;
        mega<<<dim3(e3), 256, 0, stream>>>(p, e1, e2, t1, t2, t3);
    }
}